// Round 9
// baseline (30.977 us; speedup 1.0000x reference)
//
#include <hip/hip_runtime.h>

// FRAP forward — round 9: barrier-free conv via per-wave position chains.
// R8 diagnostic: halving conv WORK saved only 1.5us -> the 7 lockstep
// __syncthreads phases ARE the conv cost, not compute. All conv layers are
// 1x1 (pointwise per spatial position) except the final (1,7) conv.
// R9: wave w of WG g runs the ENTIRE P8->P13 chain for position (i=g,k=w)
// solo (WAVE_SYNC only, no workgroup barriers), in per-wave LDS rows.
// P13 leaves h3[8] in lanes 0..7; P14 partial = 1 mul + 3 shuffles.
// Workgroup barriers: 2 total (join after early/warm, final before sum).
// Early section = R8 verbatim (wave0 solo chain || waves1-7 warm).
//
// Per-WG LDS (floats, sm[4096] = 16KB):
//   early (dead after join): feat16 @0(128) dh1 @128(2048) dh2 @2176(256)
//     dem @2432(32) ch1 @2464(1024) ch2 @3488(256)
//   conv (after join):  conv_h1 @0 (7x256)  conv_mid @1792 (7x32)
//     conv_mid2 @2016 (7x32)  conv_Hd @2240 (7x2)  partial @2254 (7)
//   dp @3968 (32) — written by wave0 P7, survives join.

#define DEV __device__ __forceinline__

// Intra-wave LDS producer->consumer fence (rule #18).
#define WAVE_SYNC() do { \
    asm volatile("s_waitcnt lgkmcnt(0)" ::: "memory"); \
    __builtin_amdgcn_sched_barrier(0); \
} while (0)

DEV float dot4a(float acc, float4 a, float4 b) {
    acc = fmaf(a.x, b.x, acc);
    acc = fmaf(a.y, b.y, acc);
    acc = fmaf(a.z, b.z, acc);
    acc = fmaf(a.w, b.w, acc);
    return acc;
}

// Coalesced cache-warm over waves 1..7 (448 threads), id = t-64.
DEV float warm_arr(const float* __restrict__ p, int n4, int id, float sink) {
    const float4* p4 = (const float4*)p;
    for (int i = id; i < n4; i += 448) {
        float4 v = p4[i];
        sink += v.x + v.y + v.z + v.w;
    }
    return sink;
}

__global__ __launch_bounds__(512, 1) void frap_kernel(
    const float* __restrict__ waiting, const float* __restrict__ phase,
    const float* __restrict__ wtime_mu, const float* __restrict__ wtime_sigma,
    const float* __restrict__ wtime_max,
    const float* __restrict__ i_pos, const float* __restrict__ j_pos,
    const float* __restrict__ d_w1, const float* __restrict__ d_b1,
    const float* __restrict__ d_w2, const float* __restrict__ d_b2,
    const float* __restrict__ d_w3, const float* __restrict__ d_b3,
    const float* __restrict__ c_w1, const float* __restrict__ c_b1,
    const float* __restrict__ c_w2, const float* __restrict__ c_b2,
    const float* __restrict__ c_w3, const float* __restrict__ c_b3,
    const float* __restrict__ dD_w1, const float* __restrict__ dD_b1,
    const float* __restrict__ dD_w2, const float* __restrict__ dD_b2,
    const float* __restrict__ dD_w3, const float* __restrict__ dD_b3,
    const float* __restrict__ cC_w1, const float* __restrict__ cC_b1,
    const float* __restrict__ cC_w2, const float* __restrict__ cC_b2,
    const float* __restrict__ cC_w3, const float* __restrict__ cC_b3,
    const float* __restrict__ cC_w4, const float* __restrict__ cC_b4,
    float* __restrict__ out)
{
    __shared__ __align__(16) float sm[4096];   // 16 KB
    const int t  = threadIdx.x;
    const int wg = blockIdx.x;                 // 0..7: output row h = wg
    const int ln = t & 63;

    float* feat16 = sm;        // 128 (8 rows x 16, cols 14/15 = 0)
    float* dh1  = sm + 128;    // 2048
    float* dh2  = sm + 2176;   // 256
    float* dem  = sm + 2432;   // 32
    float* ch1  = sm + 2464;   // 1024
    float* ch2  = sm + 3488;   // 256
    float* conv_h1   = sm;           // 7 x 256
    float* conv_mid  = sm + 1792;    // 7 x 32
    float* conv_mid2 = sm + 2016;    // 7 x 32
    float* conv_Hd   = sm + 2240;    // 7 x 2
    float* partial   = sm + 2254;    // 7
    float* dp   = sm + 3968;   // 32

    if (t < 64) {
        // ========== wave-solo early chain (identical in every WG) ==========
        // P0: feat16
        for (int rep = 0; rep < 2; ++rep) {
            int idx = rep * 64 + ln;
            int l = idx >> 4, c = idx & 15;
            float v = 0.0f;
            if      (c == 0) v = i_pos[0];
            else if (c == 1) v = j_pos[0];
            else if (c == 2) v = wtime_mu[l];
            else if (c == 3) v = wtime_sigma[l];
            else if (c == 4) v = wtime_max[l];
            else if (c == 5) v = waiting[l];
            else if (c < 14) v = phase[c - 6];
            feat16[idx] = v;
        }
        WAVE_SYNC();

        // P1: dh1[l*256+o] = relu(feat @ d_w1^T), K=14.
        for (int q = 0; q < 4; ++q) {
            int o = q * 64 + ln;
            const float* w = d_w1 + o * 14;
            float w0 = w[0], w1 = w[1], w2 = w[2], w3 = w[3], w4 = w[4];
            float w5 = w[5], w6 = w[6], w7 = w[7], w8 = w[8], w9 = w[9];
            float wa = w[10], wb = w[11], wc = w[12], wd = w[13];
            float bias = d_b1[o];
#pragma unroll
            for (int l = 0; l < 8; ++l) {
                const float4* f4 = (const float4*)(feat16 + l * 16);
                float4 f0 = f4[0], f1 = f4[1], f2 = f4[2], f3 = f4[3];
                float acc = bias;
                acc = fmaf(f0.x, w0, acc); acc = fmaf(f0.y, w1, acc);
                acc = fmaf(f0.z, w2, acc); acc = fmaf(f0.w, w3, acc);
                acc = fmaf(f1.x, w4, acc); acc = fmaf(f1.y, w5, acc);
                acc = fmaf(f1.z, w6, acc); acc = fmaf(f1.w, w7, acc);
                acc = fmaf(f2.x, w8, acc); acc = fmaf(f2.y, w9, acc);
                acc = fmaf(f2.z, wa, acc); acc = fmaf(f2.w, wb, acc);
                acc = fmaf(f3.x, wc, acc); acc = fmaf(f3.y, wd, acc);
                dh1[l * 256 + o] = fmaxf(acc, 0.0f);
            }
        }
        WAVE_SYNC();

        // P2: dh2[l*32+o], K=256. lane = (lh, o): 4 rows per lane.
        {
            int o = ln & 31, lh = ln >> 5;
            float acc0 = 0.0f, acc1 = 0.0f, acc2 = 0.0f, acc3 = 0.0f;
            const float4* w4p = (const float4*)(d_w2 + o * 256);
#pragma unroll 4
            for (int cb = 0; cb < 64; ++cb) {
                float4 w = w4p[cb];
                float4 h0 = *(const float4*)(dh1 + (lh * 4 + 0) * 256 + cb * 4);
                float4 h1 = *(const float4*)(dh1 + (lh * 4 + 1) * 256 + cb * 4);
                float4 h2 = *(const float4*)(dh1 + (lh * 4 + 2) * 256 + cb * 4);
                float4 h3v = *(const float4*)(dh1 + (lh * 4 + 3) * 256 + cb * 4);
                acc0 = dot4a(acc0, h0, w);
                acc1 = dot4a(acc1, h1, w);
                acc2 = dot4a(acc2, h2, w);
                acc3 = dot4a(acc3, h3v, w);
            }
            float b = d_b2[o];
            dh2[(lh * 4 + 0) * 32 + o] = fmaxf(acc0 + b, 0.0f);
            dh2[(lh * 4 + 1) * 32 + o] = fmaxf(acc1 + b, 0.0f);
            dh2[(lh * 4 + 2) * 32 + o] = fmaxf(acc2 + b, 0.0f);
            dh2[(lh * 4 + 3) * 32 + o] = fmaxf(acc3 + b, 0.0f);
        }
        WAVE_SYNC();

        // P3: dem (8x4), K=32.
        if (ln < 32) {
            int l = ln >> 2, o = ln & 3;
            const float4* w = (const float4*)(d_w3 + o * 32);
            const float4* h = (const float4*)(dh2 + l * 32);
            float acc = d_b3[o];
#pragma unroll
            for (int g = 0; g < 8; ++g) acc = dot4a(acc, h[g], w[g]);
            dem[ln] = acc;
        }
        WAVE_SYNC();

        // P5: ch1[p*128+o], K=8, PAIRS folded.
        for (int rep = 0; rep < 2; ++rep) {
            int o = rep * 64 + ln;
            const float4* w = (const float4*)(c_w1 + o * 8);
            float4 w0 = w[0], w1 = w[1];
            float bias = c_b1[o];
#pragma unroll
            for (int p = 0; p < 8; ++p) {
                int a0 = p & 3;
                int a1 = (p < 4) ? (4 + (p & 3)) : (4 + ((p & 3) ^ 1));
                float4 va = *(const float4*)(dem + a0 * 4);
                float4 vb = *(const float4*)(dem + a1 * 4);
                float acc = dot4a(dot4a(bias, va, w0), vb, w1);
                ch1[p * 128 + o] = fmaxf(acc, 0.0f);
            }
        }
        WAVE_SYNC();

        // P6: ch2[l*32+o], K=128.
        {
            int o = ln & 31, lh = ln >> 5;
            float acc0 = 0.0f, acc1 = 0.0f, acc2 = 0.0f, acc3 = 0.0f;
            const float4* w4p = (const float4*)(c_w2 + o * 128);
#pragma unroll 4
            for (int cb = 0; cb < 32; ++cb) {
                float4 w = w4p[cb];
                float4 h0 = *(const float4*)(ch1 + (lh * 4 + 0) * 128 + cb * 4);
                float4 h1 = *(const float4*)(ch1 + (lh * 4 + 1) * 128 + cb * 4);
                float4 h2 = *(const float4*)(ch1 + (lh * 4 + 2) * 128 + cb * 4);
                float4 h3v = *(const float4*)(ch1 + (lh * 4 + 3) * 128 + cb * 4);
                acc0 = dot4a(acc0, h0, w);
                acc1 = dot4a(acc1, h1, w);
                acc2 = dot4a(acc2, h2, w);
                acc3 = dot4a(acc3, h3v, w);
            }
            float b = c_b2[o];
            ch2[(lh * 4 + 0) * 32 + o] = fmaxf(acc0 + b, 0.0f);
            ch2[(lh * 4 + 1) * 32 + o] = fmaxf(acc1 + b, 0.0f);
            ch2[(lh * 4 + 2) * 32 + o] = fmaxf(acc2 + b, 0.0f);
            ch2[(lh * 4 + 3) * 32 + o] = fmaxf(acc3 + b, 0.0f);
        }
        WAVE_SYNC();

        // P7: dp (8x4), K=32.
        if (ln < 32) {
            int l = ln >> 2, o = ln & 3;
            const float4* w = (const float4*)(c_w3 + o * 32);
            const float4* h = (const float4*)(ch2 + l * 32);
            float acc = c_b3[o];
#pragma unroll
            for (int g = 0; g < 8; ++g) acc = dot4a(acc, h[g], w[g]);
            dp[ln] = acc;
        }
    } else {
        // ========== waves 1..7: warm full weight set into local XCD L2 ======
        int id = t - 64;    // 0..447
        float snk = 0.0f;
        snk = warm_arr(d_w1,  896, id, snk);
        snk = warm_arr(d_b1,   64, id, snk);
        snk = warm_arr(d_w2, 2048, id, snk);
        snk = warm_arr(d_b2,    8, id, snk);
        snk = warm_arr(d_w3,   32, id, snk);
        snk = warm_arr(d_b3,    1, id, snk);
        snk = warm_arr(c_w1,  256, id, snk);
        snk = warm_arr(c_b1,   32, id, snk);
        snk = warm_arr(c_w2, 1024, id, snk);
        snk = warm_arr(c_b2,    8, id, snk);
        snk = warm_arr(c_w3,   32, id, snk);
        snk = warm_arr(c_b3,    1, id, snk);
        snk = warm_arr(dD_w1, 512, id, snk);
        snk = warm_arr(dD_b1,  64, id, snk);
        snk = warm_arr(dD_w2, 2048, id, snk);
        snk = warm_arr(dD_b2,   8, id, snk);
        snk = warm_arr(dD_w3,  16, id, snk);
        snk = warm_arr(cC_w1, 192, id, snk);
        snk = warm_arr(cC_b1,  64, id, snk);
        snk = warm_arr(cC_w2, 2048, id, snk);
        snk = warm_arr(cC_b2,   8, id, snk);
        snk = warm_arr(cC_w3,  64, id, snk);
        snk = warm_arr(cC_b3,   2, id, snk);
        snk = warm_arr(cC_w4,  14, id, snk);
        asm volatile("" :: "v"(snk));
    }
    __syncthreads();   // join: dp ready, weights warm, early LDS dead

    // ====== conv section: wave w owns position (i=wg, k=w), NO barriers ====
    {
        int w = t >> 6;                       // wave id 0..7 (7 idle)
        if (w < 7) {
            const int j = w + (w >= wg ? 1 : 0);
            float* h1row = conv_h1  + w * 256;
            float* midp  = conv_mid + w * 32;
            float* mid2p = conv_mid2 + w * 32;
            float* Hdp   = conv_Hd  + w * 2;

            // P8: h1[256] = relu(dD_w1(256x8) @ [dp_i; dp_j]), 4 outs/lane.
            const float4* dp4 = (const float4*)dp;
            float4 di = dp4[wg], dj = dp4[j];
#pragma unroll
            for (int q = 0; q < 4; ++q) {
                int o = q * 64 + ln;
                const float4* wrow = (const float4*)(dD_w1 + o * 8);
                float acc = dot4a(dot4a(dD_b1[o], di, wrow[0]), dj, wrow[1]);
                h1row[o] = fmaxf(acc, 0.0f);
            }
            WAVE_SYNC();

            // P9: mid[32] = relu(dD_w2(32x256) @ h1). ch=ln>>1, kq=ln&1.
            {
                int ch = ln >> 1, kq = ln & 1;
                const float4* wp = (const float4*)(dD_w2 + ch * 256) + kq * 32;
                const float4* hp = (const float4*)h1row + kq * 32;
                float a0 = 0.0f, a1 = 0.0f, a2 = 0.0f, a3 = 0.0f;
#pragma unroll 2
                for (int e = 0; e < 32; e += 4) {
                    a0 = dot4a(a0, hp[e + 0], wp[e + 0]);
                    a1 = dot4a(a1, hp[e + 1], wp[e + 1]);
                    a2 = dot4a(a2, hp[e + 2], wp[e + 2]);
                    a3 = dot4a(a3, hp[e + 3], wp[e + 3]);
                }
                float r = (a0 + a1) + (a2 + a3);
                r += __shfl_xor(r, 1);
                if (kq == 0) midp[ch] = fmaxf(r + dD_b2[ch], 0.0f);
            }
            WAVE_SYNC();

            // P10: Hd[2] = dD_w3(2x32) @ mid (no relu). lanes 0,1.
            if (ln < 2) {
                const float4* wp = (const float4*)(dD_w3 + ln * 32);
                const float4* mp = (const float4*)midp;
                float acc = dD_b3[ln];
#pragma unroll
                for (int g = 0; g < 8; ++g) acc = dot4a(acc, mp[g], wp[g]);
                Hdp[ln] = acc;
            }
            WAVE_SYNC();

            // P11: Hc[256] = relu(cC_w1(256x3) @ [Hd0;Hd1;0]). 4 outs/lane.
            {
                float h0 = Hdp[0], h1v = Hdp[1];
#pragma unroll
                for (int q = 0; q < 4; ++q) {
                    int o = q * 64 + ln;
                    float acc = fmaf(h1v, cC_w1[o * 3 + 1],
                                     fmaf(h0, cC_w1[o * 3], cC_b1[o]));
                    h1row[o] = fmaxf(acc, 0.0f);
                }
            }
            WAVE_SYNC();

            // P12: mid2[32] = relu(cC_w2(32x256) @ Hc). Same shape as P9.
            {
                int ch = ln >> 1, kq = ln & 1;
                const float4* wp = (const float4*)(cC_w2 + ch * 256) + kq * 32;
                const float4* hp = (const float4*)h1row + kq * 32;
                float a0 = 0.0f, a1 = 0.0f, a2 = 0.0f, a3 = 0.0f;
#pragma unroll 2
                for (int e = 0; e < 32; e += 4) {
                    a0 = dot4a(a0, hp[e + 0], wp[e + 0]);
                    a1 = dot4a(a1, hp[e + 1], wp[e + 1]);
                    a2 = dot4a(a2, hp[e + 2], wp[e + 2]);
                    a3 = dot4a(a3, hp[e + 3], wp[e + 3]);
                }
                float r = (a0 + a1) + (a2 + a3);
                r += __shfl_xor(r, 1);
                if (kq == 0) mid2p[ch] = fmaxf(r + cC_b2[ch], 0.0f);
            }
            WAVE_SYNC();

            // P13: h3[8] = relu(cC_w3(8x32) @ mid2), lane o<8 holds h3[o].
            // P14 partial: p_w = sum_c cC_w4[c][w] * h3[c] via 8-lane shuffle.
            if (ln < 8) {
                const float4* wp = (const float4*)(cC_w3 + ln * 32);
                const float4* mp = (const float4*)mid2p;
                float acc = cC_b3[ln];
#pragma unroll
                for (int g = 0; g < 8; ++g) acc = dot4a(acc, mp[g], wp[g]);
                float h3v = fmaxf(acc, 0.0f);
                float p = cC_w4[ln * 7 + w] * h3v;
                p += __shfl_xor(p, 1);
                p += __shfl_xor(p, 2);
                p += __shfl_xor(p, 4);
                if (ln == 0) partial[w] = p;
            }
        }
    }
    __syncthreads();   // partials ready

    // P14 final: out[wg] = sum_w partial[w] + b4.
    if (t == 0) {
        float s = cC_b4[0];
#pragma unroll
        for (int w = 0; w < 7; ++w) s += partial[w];
        out[wg] = s;
    }
}

extern "C" void kernel_launch(void* const* d_in, const int* in_sizes, int n_in,
                              void* d_out, int out_size, void* d_ws, size_t ws_size,
                              hipStream_t stream) {
    (void)in_sizes; (void)n_in; (void)d_ws; (void)ws_size; (void)out_size;
    const float* a[33];
    for (int i = 0; i < 33; ++i) a[i] = (const float*)d_in[i];
    frap_kernel<<<dim3(8), dim3(512), 0, stream>>>(
        a[0], a[1], a[2], a[3], a[4], a[5], a[6],
        a[7], a[8], a[9], a[10], a[11], a[12],
        a[13], a[14], a[15], a[16], a[17], a[18],
        a[19], a[20], a[21], a[22], a[23], a[24],
        a[25], a[26], a[27], a[28], a[29], a[30], a[31], a[32],
        (float*)d_out);
}

// Round 10
// 25.840 us; speedup vs baseline: 1.1988x; 1.1988x over previous
//
#include <hip/hip_runtime.h>

// FRAP forward — round 10: R8 base + 2-wave early split + tiny-layer fusion.
// R9 lesson: per-wave-position conv multiplied conv-h2 weight traffic 7x
// (224KB vs 32KB/phase) -> regression. Barrier removal must preserve
// cross-position weight sharing; position-major is ONLY for tiny weights.
// R10:
//  (a) demand MLP is row-independent, coupled MLP pair-independent ->
//      wave0 = rows/pairs 0-3, wave1 = 4-7; one mid-warm __syncthreads at
//      the dem exchange (warm split A/B around it keeps overlap; R7's
//      mistake was ALL warm before the first barrier).
//  (b) fuse P10->P11 and P13->P14 position-major (weights 2x32 / 8x32 /
//      256x3 are tiny; Hd recomputed per lane, 64 MACs, broadcast reads).
//      Reduction order matches R8 exactly (4 groups of 8 + tree).
//  (c) P8, P9, P12 keep R8's weight-shared lockstep mapping verbatim.
//
// Per-WG LDS (floats, sm[4096]):
//   early: feat16 @0(128) dh1 @128(2048) dh2 @2176(256) dem @2432(32)
//          ch1 @2464(1024) ch2 @3488(256)  dp @3968(32, survives join)
//   conv:  convh @0 (7x256 swizzled)  mid @1792 (32x7 [o][sl])
//          partial @2016 (8)
// Swizzle: (sl,c) at convh[sl*256 + ((c>>2)^sl)*4 + (c&3)]  (sl<7).

#define DEV __device__ __forceinline__

#define WAVE_SYNC() do { \
    asm volatile("s_waitcnt lgkmcnt(0)" ::: "memory"); \
    __builtin_amdgcn_sched_barrier(0); \
} while (0)

DEV float dot4a(float acc, float4 a, float4 b) {
    acc = fmaf(a.x, b.x, acc);
    acc = fmaf(a.y, b.y, acc);
    acc = fmaf(a.z, b.z, acc);
    acc = fmaf(a.w, b.w, acc);
    return acc;
}

// Coalesced cache-warm over waves 2..7 (384 threads), id = t-128.
DEV float warm_arr(const float* __restrict__ p, int n4, int id, float sink) {
    const float4* p4 = (const float4*)p;
    for (int i = id; i < n4; i += 384) {
        float4 v = p4[i];
        sink += v.x + v.y + v.z + v.w;
    }
    return sink;
}

// conv h2 (R8 verbatim): convh (swizzled [sl][256]) -> relu(W(32x256)@.)
// -> mid[ch*7+sl]. 512 thr, 2-way K-split, weight rows shared across sl.
DEV void conv_h2_vec(const float* __restrict__ big, const float* __restrict__ w2g,
                     const float* __restrict__ b2g, float* __restrict__ mid, int t)
{
    int kq = t & 1;
    int u  = t >> 1;
    int ch = u >> 3, sl = u & 7;
    float a0 = 0.0f, a1 = 0.0f, a2 = 0.0f, a3 = 0.0f;
    if (sl < 7) {
        const float4* wp = (const float4*)(w2g + ch * 256) + kq * 32;
        const float* hrow = big + (sl << 8);
#pragma unroll 2
        for (int g = 0; g < 32; g += 4) {
            int gg = kq * 32 + g;
            float4 w0 = wp[g + 0], w1 = wp[g + 1], w2 = wp[g + 2], w3 = wp[g + 3];
            float4 h0 = *(const float4*)(hrow + (((gg + 0) ^ sl) << 2));
            float4 h1 = *(const float4*)(hrow + (((gg + 1) ^ sl) << 2));
            float4 h2 = *(const float4*)(hrow + (((gg + 2) ^ sl) << 2));
            float4 h3v = *(const float4*)(hrow + (((gg + 3) ^ sl) << 2));
            a0 = dot4a(a0, h0, w0);
            a1 = dot4a(a1, h1, w1);
            a2 = dot4a(a2, h2, w2);
            a3 = dot4a(a3, h3v, w3);
        }
    }
    float r = (a0 + a1) + (a2 + a3);
    r += __shfl_xor(r, 1);
    if (sl < 7 && kq == 0)
        mid[ch * 7 + sl] = fmaxf(r + b2g[ch], 0.0f);
}

__global__ __launch_bounds__(512, 1) void frap_kernel(
    const float* __restrict__ waiting, const float* __restrict__ phase,
    const float* __restrict__ wtime_mu, const float* __restrict__ wtime_sigma,
    const float* __restrict__ wtime_max,
    const float* __restrict__ i_pos, const float* __restrict__ j_pos,
    const float* __restrict__ d_w1, const float* __restrict__ d_b1,
    const float* __restrict__ d_w2, const float* __restrict__ d_b2,
    const float* __restrict__ d_w3, const float* __restrict__ d_b3,
    const float* __restrict__ c_w1, const float* __restrict__ c_b1,
    const float* __restrict__ c_w2, const float* __restrict__ c_b2,
    const float* __restrict__ c_w3, const float* __restrict__ c_b3,
    const float* __restrict__ dD_w1, const float* __restrict__ dD_b1,
    const float* __restrict__ dD_w2, const float* __restrict__ dD_b2,
    const float* __restrict__ dD_w3, const float* __restrict__ dD_b3,
    const float* __restrict__ cC_w1, const float* __restrict__ cC_b1,
    const float* __restrict__ cC_w2, const float* __restrict__ cC_b2,
    const float* __restrict__ cC_w3, const float* __restrict__ cC_b3,
    const float* __restrict__ cC_w4, const float* __restrict__ cC_b4,
    float* __restrict__ out)
{
    __shared__ __align__(16) float sm[4096];   // 16 KB
    const int t  = threadIdx.x;
    const int wg = blockIdx.x;                 // 0..7: output row h = wg
    const int wv = t >> 6;
    const int ln = t & 63;

    float* feat16 = sm;        // 128 (8 rows x 16, cols 14/15 = 0)
    float* dh1  = sm + 128;    // 2048
    float* dh2  = sm + 2176;   // 256
    float* dem  = sm + 2432;   // 32
    float* ch1  = sm + 2464;   // 1024
    float* ch2  = sm + 3488;   // 256
    float* dp   = sm + 3968;   // 32 (survives join)
    float* convh   = sm;          // 7 x 256 swizzled
    float* mid     = sm + 1792;   // 32 x 7
    float* partial = sm + 2016;   // 8

    // ================= segment 1: demand MLP (rows split) ∥ warm A ========
    if (wv < 2) {
        const int wbase = wv * 4;              // this wave's rows
        // P0: feat rows wbase..wbase+3 (64 entries per wave)
        {
            int idx = wv * 64 + ln;
            int l = idx >> 4, c = idx & 15;
            float v = 0.0f;
            if      (c == 0) v = i_pos[0];
            else if (c == 1) v = j_pos[0];
            else if (c == 2) v = wtime_mu[l];
            else if (c == 3) v = wtime_sigma[l];
            else if (c == 4) v = wtime_max[l];
            else if (c == 5) v = waiting[l];
            else if (c < 14) v = phase[c - 6];
            feat16[idx] = v;
        }
        WAVE_SYNC();

        // P1: dh1 rows wbase..+3, K=14. lane owns o = q*64+ln.
        for (int q = 0; q < 4; ++q) {
            int o = q * 64 + ln;
            const float* w = d_w1 + o * 14;
            float w0 = w[0], w1 = w[1], w2 = w[2], w3 = w[3], w4 = w[4];
            float w5 = w[5], w6 = w[6], w7 = w[7], w8 = w[8], w9 = w[9];
            float wa = w[10], wb = w[11], wc = w[12], wd = w[13];
            float bias = d_b1[o];
#pragma unroll
            for (int r = 0; r < 4; ++r) {
                int l = wbase + r;
                const float4* f4 = (const float4*)(feat16 + l * 16);
                float4 f0 = f4[0], f1 = f4[1], f2 = f4[2], f3 = f4[3];
                float acc = bias;
                acc = fmaf(f0.x, w0, acc); acc = fmaf(f0.y, w1, acc);
                acc = fmaf(f0.z, w2, acc); acc = fmaf(f0.w, w3, acc);
                acc = fmaf(f1.x, w4, acc); acc = fmaf(f1.y, w5, acc);
                acc = fmaf(f1.z, w6, acc); acc = fmaf(f1.w, w7, acc);
                acc = fmaf(f2.x, w8, acc); acc = fmaf(f2.y, w9, acc);
                acc = fmaf(f2.z, wa, acc); acc = fmaf(f2.w, wb, acc);
                acc = fmaf(f3.x, wc, acc); acc = fmaf(f3.y, wd, acc);
                dh1[l * 256 + o] = fmaxf(acc, 0.0f);
            }
        }
        WAVE_SYNC();

        // P2: dh2 rows wbase..+3, K=256. lane = (lh=ln>>5, o=ln&31), 2 rows.
        {
            int o = ln & 31, lh = ln >> 5;
            int r0 = wbase + lh * 2, r1 = r0 + 1;
            float acc0 = 0.0f, acc1 = 0.0f;
            const float4* w4p = (const float4*)(d_w2 + o * 256);
#pragma unroll 4
            for (int cb = 0; cb < 64; ++cb) {
                float4 w = w4p[cb];
                float4 h0 = *(const float4*)(dh1 + r0 * 256 + cb * 4);
                float4 h1 = *(const float4*)(dh1 + r1 * 256 + cb * 4);
                acc0 = dot4a(acc0, h0, w);
                acc1 = dot4a(acc1, h1, w);
            }
            float b = d_b2[o];
            dh2[r0 * 32 + o] = fmaxf(acc0 + b, 0.0f);
            dh2[r1 * 32 + o] = fmaxf(acc1 + b, 0.0f);
        }
        WAVE_SYNC();

        // P3: dem rows wbase..+3, K=32. lanes 0..15.
        if (ln < 16) {
            int l = wbase + (ln >> 2), o = ln & 3;
            const float4* w = (const float4*)(d_w3 + o * 32);
            const float4* h = (const float4*)(dh2 + l * 32);
            float acc = d_b3[o];
#pragma unroll
            for (int g = 0; g < 8; ++g) acc = dot4a(acc, h[g], w[g]);
            dem[l * 4 + o] = acc;
        }
    } else {
        // warm A: early + coupled weights
        int id = t - 128;    // 0..383
        float snk = 0.0f;
        snk = warm_arr(d_w1,  896, id, snk);
        snk = warm_arr(d_b1,   64, id, snk);
        snk = warm_arr(d_w2, 2048, id, snk);
        snk = warm_arr(d_b2,    8, id, snk);
        snk = warm_arr(d_w3,   32, id, snk);
        snk = warm_arr(d_b3,    1, id, snk);
        snk = warm_arr(c_w1,  256, id, snk);
        snk = warm_arr(c_b1,   32, id, snk);
        snk = warm_arr(c_w2, 1024, id, snk);
        snk = warm_arr(c_b2,    8, id, snk);
        snk = warm_arr(c_w3,   32, id, snk);
        snk = warm_arr(c_b3,    1, id, snk);
        asm volatile("" :: "v"(snk));
    }
    __syncthreads();   // dem exchange; warm A drained (harmless)

    // ================= segment 2: coupled MLP (pairs split) ∥ warm B ======
    if (wv < 2) {
        const int pbase = wv * 4;              // this wave's pairs
        // P5: ch1 rows pbase..+3, K=8, PAIRS folded.
        for (int rep = 0; rep < 2; ++rep) {
            int o = rep * 64 + ln;
            const float4* w = (const float4*)(c_w1 + o * 8);
            float4 w0 = w[0], w1 = w[1];
            float bias = c_b1[o];
#pragma unroll
            for (int pp = 0; pp < 4; ++pp) {
                int p = pbase + pp;
                int a0 = p & 3;
                int a1 = (p < 4) ? (4 + (p & 3)) : (4 + ((p & 3) ^ 1));
                float4 va = *(const float4*)(dem + a0 * 4);
                float4 vb = *(const float4*)(dem + a1 * 4);
                float acc = dot4a(dot4a(bias, va, w0), vb, w1);
                ch1[p * 128 + o] = fmaxf(acc, 0.0f);
            }
        }
        WAVE_SYNC();

        // P6: ch2 rows pbase..+3, K=128. lane = (lh, o), 2 rows.
        {
            int o = ln & 31, lh = ln >> 5;
            int r0 = pbase + lh * 2, r1 = r0 + 1;
            float acc0 = 0.0f, acc1 = 0.0f;
            const float4* w4p = (const float4*)(c_w2 + o * 128);
#pragma unroll 4
            for (int cb = 0; cb < 32; ++cb) {
                float4 w = w4p[cb];
                float4 h0 = *(const float4*)(ch1 + r0 * 128 + cb * 4);
                float4 h1 = *(const float4*)(ch1 + r1 * 128 + cb * 4);
                acc0 = dot4a(acc0, h0, w);
                acc1 = dot4a(acc1, h1, w);
            }
            float b = c_b2[o];
            ch2[r0 * 32 + o] = fmaxf(acc0 + b, 0.0f);
            ch2[r1 * 32 + o] = fmaxf(acc1 + b, 0.0f);
        }
        WAVE_SYNC();

        // P7: dp rows pbase..+3, K=32. lanes 0..15.
        if (ln < 16) {
            int p = pbase + (ln >> 2), o = ln & 3;
            const float4* w = (const float4*)(c_w3 + o * 32);
            const float4* h = (const float4*)(ch2 + p * 32);
            float acc = c_b3[o];
#pragma unroll
            for (int g = 0; g < 8; ++g) acc = dot4a(acc, h[g], w[g]);
            dp[p * 4 + o] = acc;
        }
    } else {
        // warm B: conv weights
        int id = t - 128;
        float snk = 0.0f;
        snk = warm_arr(dD_w1,  512, id, snk);
        snk = warm_arr(dD_b1,   64, id, snk);
        snk = warm_arr(dD_w2, 2048, id, snk);
        snk = warm_arr(dD_b2,    8, id, snk);
        snk = warm_arr(dD_w3,   16, id, snk);
        snk = warm_arr(cC_w1,  192, id, snk);
        snk = warm_arr(cC_b1,   64, id, snk);
        snk = warm_arr(cC_w2, 2048, id, snk);
        snk = warm_arr(cC_b2,    8, id, snk);
        snk = warm_arr(cC_w3,   64, id, snk);
        snk = warm_arr(cC_b3,    2, id, snk);
        snk = warm_arr(cC_w4,   14, id, snk);
        asm volatile("" :: "v"(snk));
    }
    __syncthreads();   // join: dp ready, weights warm

    // ============ conv section on sl 0..6 (global s = wg*7+sl) ============
    // P8 (R8 verbatim): conv_D h1, K=8 from dp. i=wg, j=sl+(sl>=wg).
    {
        const float4* dp4 = (const float4*)dp;
        int o = t & 255;
        const float4* wrow = (const float4*)(dD_w1 + o * 8);
        float4 w0 = wrow[0], w1 = wrow[1];
        float bias = dD_b1[o];
        float4 di = dp4[wg];
#pragma unroll
        for (int it = 0; it < 4; ++it) {
            int sl = (t >> 8) + it * 2;
            if (sl < 7) {
                int j = sl + (sl >= wg ? 1 : 0);
                float acc = dot4a(dot4a(bias, di, w0), dp4[j], w1);
                convh[(sl << 8) + (((o >> 2) ^ sl) << 2) + (o & 3)] = fmaxf(acc, 0.0f);
            }
        }
    }
    __syncthreads();

    // P9: conv_D h2 (32 x 7), K=256, weight-shared.
    conv_h2_vec(convh, dD_w2, dD_b2, mid, t);
    __syncthreads();

    // fused P10+P11: wave w owns sl=w. Hd recomputed per lane (tiny weights,
    // broadcast mid reads); reduction order = R8's 4x8 + tree.
    if (wv < 7) {
        const int w = wv;
        float s00 = 0.0f, s01 = 0.0f, s02 = 0.0f, s03 = 0.0f;
        float s10 = 0.0f, s11 = 0.0f, s12 = 0.0f, s13 = 0.0f;
#pragma unroll
        for (int cc = 0; cc < 8; ++cc) {
            float m0 = mid[(0 * 8 + cc) * 7 + w];
            float m1 = mid[(1 * 8 + cc) * 7 + w];
            float m2 = mid[(2 * 8 + cc) * 7 + w];
            float m3 = mid[(3 * 8 + cc) * 7 + w];
            s00 = fmaf(m0, dD_w3[0 * 32 + 0 * 8 + cc], s00);
            s01 = fmaf(m1, dD_w3[0 * 32 + 1 * 8 + cc], s01);
            s02 = fmaf(m2, dD_w3[0 * 32 + 2 * 8 + cc], s02);
            s03 = fmaf(m3, dD_w3[0 * 32 + 3 * 8 + cc], s03);
            s10 = fmaf(m0, dD_w3[1 * 32 + 0 * 8 + cc], s10);
            s11 = fmaf(m1, dD_w3[1 * 32 + 1 * 8 + cc], s11);
            s12 = fmaf(m2, dD_w3[1 * 32 + 2 * 8 + cc], s12);
            s13 = fmaf(m3, dD_w3[1 * 32 + 3 * 8 + cc], s13);
        }
        float hd0 = ((s00 + s01) + (s02 + s03)) + dD_b3[0];
        float hd1 = ((s10 + s11) + (s12 + s13)) + dD_b3[1];
        // P11: Hc[256] for sl=w; channel 2 of H_c is zero -> 2 taps.
#pragma unroll
        for (int q = 0; q < 4; ++q) {
            int o = q * 64 + ln;
            float acc = fmaf(hd1, cC_w1[o * 3 + 1],
                             fmaf(hd0, cC_w1[o * 3], cC_b1[o]));
            convh[(w << 8) + (((o >> 2) ^ w) << 2) + (o & 3)] = fmaxf(acc, 0.0f);
        }
    }
    __syncthreads();

    // P12: conv_C h2 (32 x 7), K=256, weight-shared.
    conv_h2_vec(convh, cC_w2, cC_b2, mid, t);
    __syncthreads();

    // fused P13+P14: wave w owns sl=w; lanes 0..7 = channels.
    if (wv < 7 && ln < 8) {
        const int w = wv;
        const int o = ln;
        float s0 = 0.0f, s1 = 0.0f, s2 = 0.0f, s3 = 0.0f;
#pragma unroll
        for (int cc = 0; cc < 8; ++cc) {
            s0 = fmaf(mid[(0 * 8 + cc) * 7 + w], cC_w3[o * 32 + 0 * 8 + cc], s0);
            s1 = fmaf(mid[(1 * 8 + cc) * 7 + w], cC_w3[o * 32 + 1 * 8 + cc], s1);
            s2 = fmaf(mid[(2 * 8 + cc) * 7 + w], cC_w3[o * 32 + 2 * 8 + cc], s2);
            s3 = fmaf(mid[(3 * 8 + cc) * 7 + w], cC_w3[o * 32 + 3 * 8 + cc], s3);
        }
        float h3v = fmaxf(((s0 + s1) + (s2 + s3)) + cC_b3[o], 0.0f);
        float p = cC_w4[o * 7 + w] * h3v;
        p += __shfl_xor(p, 1);
        p += __shfl_xor(p, 2);
        p += __shfl_xor(p, 4);
        if (o == 0) partial[w] = p;
    }
    __syncthreads();

    // final: out[wg] = sum_w partial[w] + b4.
    if (t == 0) {
        float s = cC_b4[0];
#pragma unroll
        for (int w = 0; w < 7; ++w) s += partial[w];
        out[wg] = s;
    }
}

extern "C" void kernel_launch(void* const* d_in, const int* in_sizes, int n_in,
                              void* d_out, int out_size, void* d_ws, size_t ws_size,
                              hipStream_t stream) {
    (void)in_sizes; (void)n_in; (void)d_ws; (void)ws_size; (void)out_size;
    const float* a[33];
    for (int i = 0; i < 33; ++i) a[i] = (const float*)d_in[i];
    frap_kernel<<<dim3(8), dim3(512), 0, stream>>>(
        a[0], a[1], a[2], a[3], a[4], a[5], a[6],
        a[7], a[8], a[9], a[10], a[11], a[12],
        a[13], a[14], a[15], a[16], a[17], a[18],
        a[19], a[20], a[21], a[22], a[23], a[24],
        a[25], a[26], a[27], a[28], a[29], a[30], a[31], a[32],
        (float*)d_out);
}